// Round 15
// baseline (209.923 us; speedup 1.0000x reference)
//
#include <hip/hip_runtime.h>
#include <hip/hip_bf16.h>

#define NN 100000   // nodes
#define KN 32       // neighbors per node
#define DD 128      // D_IN == D_OUT
#define TROWS 64              // transform block tile rows
#define TGRID ((NN + TROWS - 1) / TROWS)  // 1563
#define NCHUNK 4              // D split into 4 x 32-dim uint8 chunks
#define CDIM 32               // dims per chunk; per-chunk table = 3.2MB < 4MB L2
#define QSCALE 32.0f
#define DEQ    0.03125f
#define WBF_OFF   ((size_t)NCHUNK * NN * CDIM)   // ws offset of bf16 W
#define PROBE_OFF (WBF_OFF + 32 * 1024)          // ws offset of probe tokens

typedef __attribute__((ext_vector_type(8))) short bf16x8;
typedef __attribute__((ext_vector_type(4))) float f32x4;

__device__ __forceinline__ bf16x8 cvt8(const float4& a, const float4& b) {
  union { bf16x8 v; __hip_bfloat162 p[4]; } u;
  u.p[0] = __float22bfloat162_rn(make_float2(a.x, a.y));
  u.p[1] = __float22bfloat162_rn(make_float2(a.z, a.w));
  u.p[2] = __float22bfloat162_rn(make_float2(b.x, b.y));
  u.p[3] = __float22bfloat162_rn(make_float2(b.z, b.w));
  return u.v;
}

__device__ __forceinline__ unsigned int quant(float x) {
  x = fmaxf(x, 0.f);
  unsigned int q = (unsigned int)__builtin_rintf(x * QSCALE);
  return q > 255u ? 255u : q;
}

__device__ __forceinline__ unsigned int pack4(unsigned int q0, unsigned int q1,
                                              unsigned int q2, unsigned int q3) {
  unsigned int a = __byte_perm(q0, q1, 0x0040);
  unsigned int b = __byte_perm(q2, q3, 0x0040);
  return __byte_perm(a, b, 0x5410);
}

// ---------- shared building blocks (identical math in probes & real) -------
__device__ __forceinline__ void stage_tile(const float* F, float* lds, int r0,
                                           int w, int lane) {
#pragma unroll
  for (int i = 0; i < 8; ++i) {
    const int lbase  = w * 8192 + i * 1024;
    const int linear = lbase + lane * 16;
    const int row    = linear >> 9;
    const int colb   = linear & 511;
    const int scolb  = colb ^ ((row & 7) << 4);
    const int srow   = min(r0 + row, NN - 1);
    __builtin_amdgcn_global_load_lds(
        (const unsigned int*)((const char*)F + (size_t)srow * 512 + scolb),
        (unsigned int*)((char*)lds + lbase), 16, 0, 0);
  }
}

__device__ __forceinline__ void make_ffrag(const float* lds, bf16x8* ffrag,
                                           int w, int lane) {
  const int lr = lane & 15, q4 = lane >> 4;
  const int lkb = q4 * 32;
  const int rrow = w * 16 + lr;
  const int sw = (rrow & 7) << 4;
#pragma unroll
  for (int kt = 0; kt < 4; ++kt) {
    const int c0 = (kt * 128 + lkb) ^ sw;
    const int c1 = (kt * 128 + lkb + 16) ^ sw;
    float4 a0 = *(const float4*)((const char*)lds + rrow * 512 + c0);
    float4 a1 = *(const float4*)((const char*)lds + rrow * 512 + c1);
    ffrag[kt] = cvt8(a0, a1);
  }
}

// ---------------- Kernel 0: wbf = bf16(W), once (~2us) --------------------
__global__ __launch_bounds__(256) void k_prep(const float* __restrict__ W,
                                              bf16x8* __restrict__ wbf) {
  const int i = ((int)blockIdx.x * 256 + (int)threadIdx.x) * 8;
  float4 a = *(const float4*)(W + i);
  float4 b = *(const float4*)(W + i + 4);
  wbf[i >> 3] = cvt8(a, b);
}

// ================= ABLATION PROBES (rule #17 keep-alives) ==================
// P1: raw F->register streaming read, no LDS.
__global__ __launch_bounds__(256) void kt_reg(const float* __restrict__ F,
                                              float* __restrict__ probe) {
  const int tid = (int)threadIdx.x, lane = tid & 63, w = tid >> 6;
  const int lr = lane & 15, lk = (lane >> 4) * 8;
  const int row = min((int)blockIdx.x * TROWS + w * 16 + lr, NN - 1);
  const float* fsrc = F + (size_t)row * DD + lk;
  float s = 0.f;
#pragma unroll
  for (int kt = 0; kt < 4; ++kt) {
    float4 a = *(const float4*)(fsrc + kt * 32);
    float4 b = *(const float4*)(fsrc + kt * 32 + 4);
    s += a.x + a.y + a.z + a.w + b.x + b.y + b.z + b.w;
  }
  asm volatile("" :: "v"(s));
  if (tid == 0) probe[blockIdx.x] = s;
}

// P2: glds staging + barrier drain only.
__global__ __launch_bounds__(256) void kt_stage(const float* __restrict__ F,
                                                float* __restrict__ probe) {
  __shared__ float lds[TROWS * DD];
  const int tid = (int)threadIdx.x;
  stage_tile(F, lds, (int)blockIdx.x * TROWS, tid >> 6, tid & 63);
  __syncthreads();
  float v = lds[tid * 8];
  asm volatile("" :: "v"(v));
  if (tid == 0) probe[blockIdx.x] = v;
}

// P3: + swizzled ds_read_b128 + cvt (A fragments).
__global__ __launch_bounds__(256) void kt_frag(const float* __restrict__ F,
                                               float* __restrict__ probe) {
  __shared__ float lds[TROWS * DD];
  const int tid = (int)threadIdx.x, lane = tid & 63, w = tid >> 6;
  stage_tile(F, lds, (int)blockIdx.x * TROWS, w, lane);
  __syncthreads();
  bf16x8 ffrag[4];
  make_ffrag(lds, ffrag, w, lane);
  unsigned int tok = 0;
#pragma unroll
  for (int kt = 0; kt < 4; ++kt)
#pragma unroll
    for (int d = 0; d < 4; ++d) tok ^= ((const unsigned int*)&ffrag[kt])[d];
  asm volatile("" :: "v"(tok));
  if (tid == 0) probe[blockIdx.x] = (float)tok;
}

// P4: + the per-wave W fragment loads (32KB of wbf per wave).
__global__ __launch_bounds__(256) void kt_wload(
    const float* __restrict__ F, const unsigned short* __restrict__ wbf,
    float* __restrict__ probe) {
  __shared__ float lds[TROWS * DD];
  const int tid = (int)threadIdx.x, lane = tid & 63, w = tid >> 6;
  stage_tile(F, lds, (int)blockIdx.x * TROWS, w, lane);
  __syncthreads();
  bf16x8 ffrag[4];
  make_ffrag(lds, ffrag, w, lane);
  const int lr = lane & 15, q4 = lane >> 4;
  unsigned int tok = 0;
#pragma unroll
  for (int kt = 0; kt < 4; ++kt)
#pragma unroll
    for (int d = 0; d < 4; ++d) tok ^= ((const unsigned int*)&ffrag[kt])[d];
#pragma unroll
  for (int nt = 0; nt < 8; ++nt) {
    const unsigned short* bsrc = wbf + (size_t)(nt * 16 + lr) * DD + q4 * 8;
#pragma unroll
    for (int kt = 0; kt < 4; ++kt) {
      bf16x8 v = *(const bf16x8*)(bsrc + kt * 32);
#pragma unroll
      for (int d = 0; d < 4; ++d) tok ^= ((const unsigned int*)&v)[d];
    }
  }
  asm volatile("" :: "v"(tok));
  if (tid == 0) probe[blockIdx.x] = (float)tok;
}

// P5: + all 32 MFMAs (token store, no hq epilogue).
__global__ __launch_bounds__(256) void kt_mfma(
    const float* __restrict__ F, const unsigned short* __restrict__ wbf,
    float* __restrict__ probe) {
  __shared__ float lds[TROWS * DD];
  const int tid = (int)threadIdx.x, lane = tid & 63, w = tid >> 6;
  stage_tile(F, lds, (int)blockIdx.x * TROWS, w, lane);
  __syncthreads();
  bf16x8 ffrag[4];
  make_ffrag(lds, ffrag, w, lane);
  const int lr = lane & 15, q4 = lane >> 4;
  f32x4 acc[8];
#pragma unroll
  for (int nt = 0; nt < 8; ++nt) acc[nt] = (f32x4){0.f, 0.f, 0.f, 0.f};
#pragma unroll
  for (int h = 0; h < 2; ++h) {
    bf16x8 wfrag[4][4];
#pragma unroll
    for (int n = 0; n < 4; ++n) {
      const unsigned short* bsrc =
          wbf + (size_t)((h * 4 + n) * 16 + lr) * DD + q4 * 8;
#pragma unroll
      for (int kt = 0; kt < 4; ++kt) wfrag[n][kt] = *(const bf16x8*)(bsrc + kt * 32);
    }
#pragma unroll
    for (int n = 0; n < 4; ++n)
#pragma unroll
      for (int kt = 0; kt < 4; ++kt)
        acc[h * 4 + n] = __builtin_amdgcn_mfma_f32_16x16x32_bf16(
            wfrag[n][kt], ffrag[kt], acc[h * 4 + n], 0, 0, 0);
  }
  float s = 0.f;
#pragma unroll
  for (int nt = 0; nt < 8; ++nt) s += acc[nt][0] + acc[nt][1] + acc[nt][2] + acc[nt][3];
  asm volatile("" :: "v"(s));
  if (tid == 0) probe[blockIdx.x] = s;
}

// ================= REAL transform (R14, swapped-operand) ===================
__global__ __launch_bounds__(256) void k_transform(
    const float* __restrict__ F, const unsigned short* __restrict__ wbf,
    const float* __restrict__ bias, unsigned char* __restrict__ hq) {
  __shared__ float lds[TROWS * DD];
  const int tid = (int)threadIdx.x, lane = tid & 63, w = tid >> 6;
  const int r0 = (int)blockIdx.x * TROWS;
  stage_tile(F, lds, r0, w, lane);
  __syncthreads();
  bf16x8 ffrag[4];
  make_ffrag(lds, ffrag, w, lane);
  const int lr = lane & 15, q4 = lane >> 4;
  f32x4 acc[8];
#pragma unroll
  for (int nt = 0; nt < 8; ++nt) acc[nt] = (f32x4){0.f, 0.f, 0.f, 0.f};
#pragma unroll
  for (int h = 0; h < 2; ++h) {
    bf16x8 wfrag[4][4];
#pragma unroll
    for (int n = 0; n < 4; ++n) {
      const unsigned short* bsrc =
          wbf + (size_t)((h * 4 + n) * 16 + lr) * DD + q4 * 8;
#pragma unroll
      for (int kt = 0; kt < 4; ++kt) wfrag[n][kt] = *(const bf16x8*)(bsrc + kt * 32);
    }
#pragma unroll
    for (int n = 0; n < 4; ++n)
#pragma unroll
      for (int kt = 0; kt < 4; ++kt)
        acc[h * 4 + n] = __builtin_amdgcn_mfma_f32_16x16x32_bf16(
            wfrag[n][kt], ffrag[kt], acc[h * 4 + n], 0, 0, 0);
  }
  const int node = r0 + w * 16 + lr;
  if (node < NN) {
#pragma unroll
    for (int nt = 0; nt < 8; ++nt) {
      const float4 b4 = *(const float4*)(bias + nt * 16 + q4 * 4);
      const unsigned int p = pack4(quant(acc[nt][0] + b4.x),
                                   quant(acc[nt][1] + b4.y),
                                   quant(acc[nt][2] + b4.z),
                                   quant(acc[nt][3] + b4.w));
      *(unsigned int*)(hq + ((size_t)(nt >> 1) * NN + node) * CDIM +
                       (nt & 1) * 16 + q4 * 4) = p;
    }
  }
}

// ================= gather (R10-exact) ======================================
__global__ __launch_bounds__(256) void k_gather_chunk(
    const int* __restrict__ nbr, const unsigned char* __restrict__ hq,
    float* __restrict__ out, int chunk) {
  const int lane = (int)(threadIdx.x & 63);
  const int wv   = (int)(threadIdx.x >> 6);
  const int g    = lane >> 3;
  const int dp   = lane & 7;
  const int node = ((int)blockIdx.x * 4 + wv) * 8 + g;

  int nv[4];
#pragma unroll
  for (int s = 0; s < 4; ++s)
    nv[s] = nbr[(size_t)node * KN + s * 8 + dp];

  const unsigned char* tab = hq + (size_t)chunk * NN * CDIM;
  unsigned int u[KN];
#pragma unroll
  for (int j = 0; j < KN; ++j) {
    const int src = (g << 3) | (j & 7);
    const int idx = __shfl(nv[j >> 3], src);
    u[j] = *(const unsigned int*)(tab + (size_t)idx * CDIM + dp * 4);
  }
  unsigned int m0 = 0u, m1 = 0u, m2 = 0u, m3 = 0u;
#pragma unroll
  for (int j = 0; j < KN; ++j) {
    m0 = max(m0, u[j] & 0xffu);
    m1 = max(m1, (u[j] >> 8) & 0xffu);
    m2 = max(m2, (u[j] >> 16) & 0xffu);
    m3 = max(m3, u[j] >> 24);
  }
  f32x4 r;
  r[0] = (float)m0 * DEQ;
  r[1] = (float)m1 * DEQ;
  r[2] = (float)m2 * DEQ;
  r[3] = (float)m3 * DEQ;
  *(f32x4*)(out + (size_t)node * DD + chunk * CDIM + dp * 4) = r;
}

extern "C" void kernel_launch(void* const* d_in, const int* in_sizes, int n_in,
                              void* d_out, int out_size, void* d_ws, size_t ws_size,
                              hipStream_t stream) {
  const float* F    = (const float*)d_in[0];
  const int*   nbr  = (const int*)d_in[1];
  const float* W    = (const float*)d_in[2];
  const float* bias = (const float*)d_in[3];
  float* out = (float*)d_out;
  unsigned char* hq = (unsigned char*)d_ws;
  unsigned short* wbf = (unsigned short*)((char*)d_ws + WBF_OFF);
  float* probe = (float*)((char*)d_ws + PROBE_OFF);

  k_prep<<<8, 256, 0, stream>>>(W, (bf16x8*)wbf);
  // ---- ablation probes (per-dispatch durations via rocprof) ----
  kt_reg  <<<TGRID, 256, 0, stream>>>(F, probe);
  kt_stage<<<TGRID, 256, 0, stream>>>(F, probe + 2048);
  kt_frag <<<TGRID, 256, 0, stream>>>(F, probe + 4096);
  kt_wload<<<TGRID, 256, 0, stream>>>(F, wbf, probe + 6144);
  kt_mfma <<<TGRID, 256, 0, stream>>>(F, wbf, probe + 8192);
  // ---- real pipeline ----
  k_transform<<<TGRID, 256, 0, stream>>>(F, wbf, bias, hq);
  for (int c = 0; c < NCHUNK; ++c)
    k_gather_chunk<<<NN / 32, 256, 0, stream>>>(nbr, hq, out, c);
}